// Round 5
// baseline (123.760 us; speedup 1.0000x reference)
//
#include <hip/hip_runtime.h>

namespace {

typedef float f32x4 __attribute__((ext_vector_type(4)));
typedef short bf16x8 __attribute__((ext_vector_type(8)));

constexpr int Bn = 64, QN = 16, Dn = 64, DVn = 64, KVn = 16384;
constexpr int MAX_SPLITS = 32;
constexpr int TILE = 64;        // keys per block-tile (16 per wave)
constexpr int THREADS = 256;    // 4 independent waves
constexpr int PTP = 20;         // pT row pitch in words (80 B, 16B-aligned cols)

constexpr float SCALE = 0.125f * 1.4426950408889634f;  // 1/sqrt(64) * log2(e)

__device__ __forceinline__ unsigned cvt_pk_bf16(float a, float b) {
    unsigned r;
    asm("v_cvt_pk_bf16_f32 %0, %1, %2" : "=v"(r) : "v"(a), "v"(b));
    return r;
}

union FragU { unsigned u[4]; bf16x8 v; };

// split 8 fp32 into hi/lo bf16x8 fragments (hi = rne-bf16, lo = bf16(x - hi))
__device__ __forceinline__ void split8(const float* x, bf16x8& hi, bf16x8& lo) {
    FragU uh, ul;
#pragma unroll
    for (int p = 0; p < 4; ++p) {
        const float a = x[2 * p], b = x[2 * p + 1];
        const unsigned h = cvt_pk_bf16(a, b);
        uh.u[p] = h;
        const float ha = __uint_as_float(h << 16);
        const float hb = __uint_as_float(h & 0xffff0000u);
        ul.u[p] = cvt_pk_bf16(a - ha, b - hb);
    }
    hi = uh.v; lo = ul.v;
}

// QK^T (hi/lo split, 3 MFMA per K=32 step) + softmax over q for one 16-key
// tile. kp = lane's key row (key = l15) at element offset g*8. Returns this
// lane's 4 probs (q = g*4+r) at key l15. Wave-local (validated r4 layout:
// C/D col=l15=key, row=g*4+r=q; softmax over q = own-4 + xor16 + xor32).
__device__ __forceinline__ f32x4 qk_softmax(const float* kp,
                                            const bf16x8 qhi[2],
                                            const bf16x8 qlo[2]) {
    f32x4 sacc = {0.f, 0.f, 0.f, 0.f};
#pragma unroll
    for (int ks = 0; ks < 2; ++ks) {
        const float4 a = *reinterpret_cast<const float4*>(kp + ks * 32);
        const float4 b = *reinterpret_cast<const float4*>(kp + ks * 32 + 4);
        float x[8] = {a.x, a.y, a.z, a.w, b.x, b.y, b.z, b.w};
        bf16x8 khi, klo;
        split8(x, khi, klo);
        sacc = __builtin_amdgcn_mfma_f32_16x16x32_bf16(qhi[ks], khi, sacc, 0, 0, 0);
        sacc = __builtin_amdgcn_mfma_f32_16x16x32_bf16(qhi[ks], klo, sacc, 0, 0, 0);
        sacc = __builtin_amdgcn_mfma_f32_16x16x32_bf16(qlo[ks], khi, sacc, 0, 0, 0);
    }
    float m = fmaxf(fmaxf(sacc[0], sacc[1]), fmaxf(sacc[2], sacc[3]));
    m = fmaxf(m, __shfl_xor(m, 16, 64));
    m = fmaxf(m, __shfl_xor(m, 32, 64));
    f32x4 pr;
    pr[0] = exp2f(sacc[0] - m); pr[1] = exp2f(sacc[1] - m);
    pr[2] = exp2f(sacc[2] - m); pr[3] = exp2f(sacc[3] - m);
    float s = pr[0] + pr[1] + pr[2] + pr[3];
    s += __shfl_xor(s, 16, 64);
    s += __shfl_xor(s, 32, 64);
    const float inv = 1.0f / s;
    pr[0] *= inv; pr[1] *= inv; pr[2] *= inv; pr[3] *= inv;
    return pr;
}

// Barrier-free: each wave is an independent split over its own 16 keys/tile.
__global__ __launch_bounds__(THREADS, 4)
void inv_attn_part(const float* __restrict__ query,
                   const float* __restrict__ key,
                   const float* __restrict__ value,
                   float* __restrict__ pout,   // [B][splits*4][QN][DVn]
                   float* __restrict__ pden,   // [B][splits*4][QN]
                   int npairs)                 // tile-pairs per wave
{
    // per-wave P^T scratch: rows = pair-key 0..31, cols = q. Wave-private:
    // same-wave LDS write->read needs no barrier (validated r2-r4).
    __shared__ __align__(16) float pT[4][32 * PTP];   // 10.2 KB total

    const int tid = threadIdx.x;
    const int lane = tid & 63;
    const int w = tid >> 6;
    const int l15 = lane & 15;
    const int g = lane >> 4;
    const int spl = blockIdx.x;
    const int splits = gridDim.x;
    const int b = blockIdx.y;
    // this wave's first key row
    const int kt0 = spl * (npairs * 2 * TILE) + w * 16;

    // ---- hoist Q fragments (A-frag: row=l15=q, k=ks*32+g*8+j; validated) ----
    bf16x8 qhi[2], qlo[2];
    {
        const float* qp = query + ((size_t)b * QN + l15) * Dn + g * 8;
#pragma unroll
        for (int ks = 0; ks < 2; ++ks) {
            const float4 u0 = *reinterpret_cast<const float4*>(qp + ks * 32);
            const float4 u1 = *reinterpret_cast<const float4*>(qp + ks * 32 + 4);
            float x[8] = {u0.x * SCALE, u0.y * SCALE, u0.z * SCALE, u0.w * SCALE,
                          u1.x * SCALE, u1.y * SCALE, u1.z * SCALE, u1.w * SCALE};
            split8(x, qhi[ks], qlo[ks]);
        }
    }

    // K: lane's key row (key=l15), elems g*8.. ; advances 128 rows per pair.
    const float* kp = key + ((size_t)b * KVn + kt0 + l15) * Dn + g * 8;
    // V: per-lane base so all 32 scalar loads/pair are imm offsets.
    // pair-key pk = g*8+j -> row = (g&1)*8 + (g>>1)*64 + j ; dv = c*16 + l15.
    const float* vp = value + ((size_t)b * KVn + kt0 + (g & 1) * 8 + (g >> 1) * TILE) * Dn + l15;
    float* pTw = &pT[w][0];

    f32x4 o0 = {0.f,0.f,0.f,0.f}, o1 = {0.f,0.f,0.f,0.f},
          o2 = {0.f,0.f,0.f,0.f}, o3 = {0.f,0.f,0.f,0.f};
    f32x4 den = {0.f,0.f,0.f,0.f};

    for (int p = 0; p < npairs; ++p) {
        // ---- QK^T + softmax, two tiles (keys pk 0..15 and 16..31) ----
        const f32x4 pA = qk_softmax(kp, qhi, qlo);
        const f32x4 pB = qk_softmax(kp + 64 * Dn, qhi, qlo);
        den[0] += pA[0] + pB[0]; den[1] += pA[1] + pB[1];
        den[2] += pA[2] + pB[2]; den[3] += pA[3] + pB[3];

        // ---- transpose P via wave-private LDS: pT[pk][q] ----
        *reinterpret_cast<f32x4*>(&pTw[l15 * PTP + g * 4]) = pA;
        *reinterpret_cast<f32x4*>(&pTw[(16 + l15) * PTP + g * 4]) = pB;

        // ---- A-frag for PV: row=l15=q, k = pk = g*8+j ----
        float ax[8];
#pragma unroll
        for (int j = 0; j < 8; ++j) ax[j] = pTw[(g * 8 + j) * PTP + l15];
        FragU ua;
        ua.u[0] = cvt_pk_bf16(ax[0], ax[1]);
        ua.u[1] = cvt_pk_bf16(ax[2], ax[3]);
        ua.u[2] = cvt_pk_bf16(ax[4], ax[5]);
        ua.u[3] = cvt_pk_bf16(ax[6], ax[7]);

        // ---- V B-frags (col=l15=dv, k=pk) + PV MFMA, 4 dv-chunks ----
#define PV_CHUNK(c, oc) {                                                     \
        float vx[8];                                                          \
        _Pragma("unroll")                                                     \
        for (int j = 0; j < 8; ++j) vx[j] = vp[j * Dn + (c) * 16];            \
        FragU uv;                                                             \
        uv.u[0] = cvt_pk_bf16(vx[0], vx[1]);                                  \
        uv.u[1] = cvt_pk_bf16(vx[2], vx[3]);                                  \
        uv.u[2] = cvt_pk_bf16(vx[4], vx[5]);                                  \
        uv.u[3] = cvt_pk_bf16(vx[6], vx[7]);                                  \
        oc = __builtin_amdgcn_mfma_f32_16x16x32_bf16(ua.v, uv.v, oc, 0, 0, 0); }
        PV_CHUNK(0, o0)
        PV_CHUNK(1, o1)
        PV_CHUNK(2, o2)
        PV_CHUNK(3, o3)
#undef PV_CHUNK

        kp += 128 * Dn;
        vp += 128 * Dn;
    }

    // ---- write this wave's partial O (split id = spl*4 + w) ----
    const int s4 = spl * 4 + w;
    const size_t obase = (((size_t)b * (splits * 4) + s4) * QN) * DVn;
#pragma unroll
    for (int r = 0; r < 4; ++r) {
        const int q = g * 4 + r;
        pout[obase + q * DVn +  0 + l15] = o0[r];
        pout[obase + q * DVn + 16 + l15] = o1[r];
        pout[obase + q * DVn + 32 + l15] = o2[r];
        pout[obase + q * DVn + 48 + l15] = o3[r];
    }

    // ---- denominator: reduce over the 16 keys (l15 axis) ----
#pragma unroll
    for (int off = 1; off < 16; off <<= 1) {
        den[0] += __shfl_xor(den[0], off, 64);
        den[1] += __shfl_xor(den[1], off, 64);
        den[2] += __shfl_xor(den[2], off, 64);
        den[3] += __shfl_xor(den[3], off, 64);
    }
    if (l15 == 0) {
        const size_t dbase = ((size_t)b * (splits * 4) + s4) * QN + g * 4;
        pden[dbase + 0] = den[0];
        pden[dbase + 1] = den[1];
        pden[dbase + 2] = den[2];
        pden[dbase + 3] = den[3];
    }
}

__global__ __launch_bounds__(256)
void inv_attn_reduce(const float* __restrict__ pout,
                     const float* __restrict__ pden,
                     float* __restrict__ out,
                     int splits4)
{
    const int gid = blockIdx.x * blockDim.x + threadIdx.x;   // 0..65535
    const int dv = gid & 63;
    const int q  = (gid >> 6) & (QN - 1);
    const int b  = gid >> 10;
    float sum = 0.f, den = 0.f;
#pragma unroll 4
    for (int sp = 0; sp < splits4; ++sp) {
        sum += pout[(((size_t)b * splits4 + sp) * QN + q) * DVn + dv];
        den += pden[((size_t)b * splits4 + sp) * QN + q];
    }
    out[gid] = sum / (den + 1e-8f);
}

}  // namespace

extern "C" void kernel_launch(void* const* d_in, const int* in_sizes, int n_in,
                              void* d_out, int out_size, void* d_ws, size_t ws_size,
                              hipStream_t stream) {
    const float* query = (const float*)d_in[0];
    const float* key   = (const float*)d_in[1];
    const float* value = (const float*)d_in[2];
    float* out = (float*)d_out;

    // Largest split count whose per-WAVE partials (4 per block) fit in d_ws.
    int splits = MAX_SPLITS;
    auto need = [](int s) {
        return (size_t)Bn * s * 4 * QN * DVn * sizeof(float)
             + (size_t)Bn * s * 4 * QN * sizeof(float);
    };
    while (splits > 1 && need(splits) > ws_size) splits >>= 1;

    float* pout = (float*)d_ws;
    float* pden = pout + (size_t)Bn * (splits * 4) * QN * DVn;

    const int npairs = KVn / (splits * TILE * 2);   // tile-pairs per wave

    dim3 grid1(splits, Bn);
    inv_attn_part<<<grid1, THREADS, 0, stream>>>(query, key, value, pout, pden, npairs);

    const int total = Bn * QN * DVn;   // 65536
    inv_attn_reduce<<<total / 256, 256, 0, stream>>>(pout, pden, out, splits * 4);
}

// Round 6
// 121.227 us; speedup vs baseline: 1.0209x; 1.0209x over previous
//
#include <hip/hip_runtime.h>

namespace {

typedef float f32x4 __attribute__((ext_vector_type(4)));
typedef short bf16x8 __attribute__((ext_vector_type(8)));

constexpr int Bn = 64, QN = 16, Dn = 64, DVn = 64, KVn = 16384;
constexpr int MAX_SPLITS = 32;
constexpr int TILE = 64;        // keys per block-tile (16 per wave for QK)
constexpr int THREADS = 256;    // 4 waves
constexpr int AP   = 68;        // a_s row pitch (floats): 272B = 17*16B
constexpr int VROW = 160;       // vT row pitch in BYTES: 128B data + 32B pad

constexpr float SCALE = 0.125f * 1.4426950408889634f;  // 1/sqrt(64) * log2(e)

__device__ __forceinline__ unsigned cvt_pk_bf16(float a, float b) {
    unsigned r;
    asm("v_cvt_pk_bf16_f32 %0, %1, %2" : "=v"(r) : "v"(a), "v"(b));
    return r;
}

union FragU { unsigned u[4]; bf16x8 v; };

// split 8 fp32 into hi/lo bf16x8 fragments (hi = rne-bf16, lo = bf16(x - hi))
__device__ __forceinline__ void split8(const float* x, bf16x8& hi, bf16x8& lo) {
    FragU uh, ul;
#pragma unroll
    for (int p = 0; p < 4; ++p) {
        const float a = x[2 * p], b = x[2 * p + 1];
        const unsigned h = cvt_pk_bf16(a, b);
        uh.u[p] = h;
        const float ha = __uint_as_float(h << 16);
        const float hb = __uint_as_float(h & 0xffff0000u);
        ul.u[p] = cvt_pk_bf16(a - ha, b - hb);
    }
    hi = uh.v; lo = ul.v;
}

__global__ __launch_bounds__(THREADS, 4)
void inv_attn_part(const float* __restrict__ query,
                   const float* __restrict__ key,
                   const float* __restrict__ value,
                   float* __restrict__ pout,   // [B][splits][QN][DVn]  (per block)
                   float* __restrict__ pden,   // [B][splits*4][QN]     (per wave)
                   int ntiles)
{
    // dbuf'd cross-wave buffers; 1 barrier per tile (validated r4).
    __shared__ __align__(16) float a_s[2][QN * AP];     // P[q][key], fp32
    __shared__ __align__(16) char  vT[2][DVn * VROW];   // V^T bf16, swizzled

    const int tid  = threadIdx.x;
    const int lane = tid & 63;
    const int w    = tid >> 6;
    const int l15  = lane & 15;
    const int g    = lane >> 4;
    const int spl  = blockIdx.x;
    const int splits = gridDim.x;
    const int b    = blockIdx.y;
    const int kt0  = spl * ntiles * TILE;

    // ---- hoist Q fragments (A-frag row=l15=q, k=ks*32+g*8+j; validated) ----
    bf16x8 qhi[2], qlo[2];
    {
        const float* qp = query + ((size_t)b * QN + l15) * Dn + g * 8;
#pragma unroll
        for (int ks = 0; ks < 2; ++ks) {
            const float4 u0 = *reinterpret_cast<const float4*>(qp + ks * 32);
            const float4 u1 = *reinterpret_cast<const float4*>(qp + ks * 32 + 4);
            float x[8] = {u0.x * SCALE, u0.y * SCALE, u0.z * SCALE, u0.w * SCALE,
                          u1.x * SCALE, u1.y * SCALE, u1.z * SCALE, u1.w * SCALE};
            split8(x, qhi[ks], qlo[ks]);
        }
    }

    // K: this wave's QK key row (key = w*16+l15), element offset g*8.
    const float* kbase = key + ((size_t)b * KVn + kt0 + w * 16 + l15) * Dn + g * 8;
    // V staging map (coalesced float4): thread stages rows vkey+16i, cols vdv0..+3.
    const int vkey = tid >> 4;
    const int vdv0 = (tid & 15) * 4;
    const int vsw  = ((tid & 15) & 7) << 4;     // XOR swizzle = ((dv>>2)&7)<<4
    const float* vbase = value + ((size_t)b * KVn + kt0 + vkey) * Dn + vdv0;

    f32x4 oacc = {0.f, 0.f, 0.f, 0.f};   // O[q=g*4+r][dv=w*16+l15]
    f32x4 den  = {0.f, 0.f, 0.f, 0.f};   // wave-partial denom, q=g*4+r

    // ---- double-buffered register prefetch (static names, no dyn reg idx) ----
    float4 kA[4], vA[4], kB[4], vB[4];
#pragma unroll
    for (int h = 0; h < 4; ++h)
        kA[h] = *reinterpret_cast<const float4*>(kbase + (h >> 1) * 32 + (h & 1) * 4);
#pragma unroll
    for (int i = 0; i < 4; ++i)
        vA[i] = *reinterpret_cast<const float4*>(vbase + (size_t)(16 * i) * Dn);

    auto body = [&](int t, int buf, float4 (&kc)[4], float4 (&vc)[4],
                    float4 (&kn)[4], float4 (&vn)[4]) {
        // 1. commit this tile's V (regs, loaded last iter) to vT[buf]
#pragma unroll
        for (int i = 0; i < 4; ++i) {
            const int kk = vkey + 16 * i;
#pragma unroll
            for (int j = 0; j < 4; ++j) {
                const float xv = (j == 0) ? vc[i].x : (j == 1) ? vc[i].y
                                : (j == 2) ? vc[i].z : vc[i].w;
                *reinterpret_cast<short*>(
                    &vT[buf][(vdv0 + j) * VROW + ((2 * kk) ^ vsw)]) =
                    (short)cvt_pk_bf16(xv, xv);
            }
        }

        // 2. ISSUE next tile's loads now; they drain at the barrier below,
        //    a full QK+softmax phase after issue (latency hidden).
        if (t + 1 < ntiles) {
            const size_t koff = (size_t)(t + 1) * TILE * Dn;
#pragma unroll
            for (int h = 0; h < 4; ++h)
                kn[h] = *reinterpret_cast<const float4*>(
                    kbase + koff + (h >> 1) * 32 + (h & 1) * 4);
#pragma unroll
            for (int i = 0; i < 4; ++i)
                vn[i] = *reinterpret_cast<const float4*>(
                    vbase + koff + (size_t)(16 * i) * Dn);
        }

        // 3. QK^T from kc (hi/lo split, 3 MFMA per K=32 step)
        f32x4 sacc = {0.f, 0.f, 0.f, 0.f};
#pragma unroll
        for (int ks = 0; ks < 2; ++ks) {
            const float4 a = kc[ks * 2], c = kc[ks * 2 + 1];
            float x[8] = {a.x, a.y, a.z, a.w, c.x, c.y, c.z, c.w};
            bf16x8 khi, klo;
            split8(x, khi, klo);
            sacc = __builtin_amdgcn_mfma_f32_16x16x32_bf16(qhi[ks], khi, sacc, 0, 0, 0);
            sacc = __builtin_amdgcn_mfma_f32_16x16x32_bf16(qhi[ks], klo, sacc, 0, 0, 0);
            sacc = __builtin_amdgcn_mfma_f32_16x16x32_bf16(qlo[ks], khi, sacc, 0, 0, 0);
        }

        // 4. softmax over q (16) at key = w*16+l15 (validated layout)
        float m = fmaxf(fmaxf(sacc[0], sacc[1]), fmaxf(sacc[2], sacc[3]));
        m = fmaxf(m, __shfl_xor(m, 16, 64));
        m = fmaxf(m, __shfl_xor(m, 32, 64));
        float p0 = exp2f(sacc[0] - m), p1 = exp2f(sacc[1] - m);
        float p2 = exp2f(sacc[2] - m), p3 = exp2f(sacc[3] - m);
        float s = p0 + p1 + p2 + p3;
        s += __shfl_xor(s, 16, 64);
        s += __shfl_xor(s, 32, 64);
        const float inv = 1.0f / s;
        p0 *= inv; p1 *= inv; p2 *= inv; p3 *= inv;
        const int kloc = w * 16 + l15;
        a_s[buf][(g * 4 + 0) * AP + kloc] = p0;
        a_s[buf][(g * 4 + 1) * AP + kloc] = p1;
        a_s[buf][(g * 4 + 2) * AP + kloc] = p2;
        a_s[buf][(g * 4 + 3) * AP + kloc] = p3;
        den[0] += p0; den[1] += p1; den[2] += p2; den[3] += p3;

        // 5. one barrier per tile: publishes a_s/vT[buf], retires prefetch
        __syncthreads();

        // 6. PV: O[q][dv] += P[q][key] * V[key][dv]
#pragma unroll
        for (int ks = 0; ks < 2; ++ks) {
            const int base = ks * 32 + g * 8;
            const float4 a0 = *reinterpret_cast<const float4*>(&a_s[buf][l15 * AP + base]);
            const float4 a1 = *reinterpret_cast<const float4*>(&a_s[buf][l15 * AP + base + 4]);
            FragU ua;
            ua.u[0] = cvt_pk_bf16(a0.x, a0.y);
            ua.u[1] = cvt_pk_bf16(a0.z, a0.w);
            ua.u[2] = cvt_pk_bf16(a1.x, a1.y);
            ua.u[3] = cvt_pk_bf16(a1.z, a1.w);
            const int dv = w * 16 + l15;
            const int gran = (((ks * 4 + g) ^ ((dv >> 2) & 7)) << 4);
            const bf16x8 vf = *reinterpret_cast<const bf16x8*>(&vT[buf][dv * VROW + gran]);
            oacc = __builtin_amdgcn_mfma_f32_16x16x32_bf16(ua.v, vf, oacc, 0, 0, 0);
        }
    };

    for (int t = 0; t < ntiles; t += 2) {   // ntiles is even (>=2)
        body(t,     0, kA, vA, kB, vB);
        body(t + 1, 1, kB, vB, kA, vA);
    }

    // ---- per-block partial O ----
    const size_t obase = (((size_t)b * splits + spl) * QN) * DVn;
    const int dv = w * 16 + l15;
#pragma unroll
    for (int r = 0; r < 4; ++r)
        pout[obase + (g * 4 + r) * DVn + dv] = oacc[r];

    // ---- per-wave denom: reduce over 16 keys (l15 axis) ----
#pragma unroll
    for (int off = 1; off < 16; off <<= 1) {
        den[0] += __shfl_xor(den[0], off, 64);
        den[1] += __shfl_xor(den[1], off, 64);
        den[2] += __shfl_xor(den[2], off, 64);
        den[3] += __shfl_xor(den[3], off, 64);
    }
    if (l15 == 0) {
        const size_t dbase = ((size_t)b * (splits * 4) + spl * 4 + w) * QN + g * 4;
        pden[dbase + 0] = den[0];
        pden[dbase + 1] = den[1];
        pden[dbase + 2] = den[2];
        pden[dbase + 3] = den[3];
    }
}

__global__ __launch_bounds__(256)
void inv_attn_reduce(const float* __restrict__ pout,
                     const float* __restrict__ pden,
                     float* __restrict__ out,
                     int splits)
{
    const int gid = blockIdx.x * blockDim.x + threadIdx.x;   // 0..65535
    const int dv = gid & 63;
    const int q  = (gid >> 6) & (QN - 1);
    const int b  = gid >> 10;
    float sum = 0.f, den = 0.f;
#pragma unroll 4
    for (int sp = 0; sp < splits; ++sp)
        sum += pout[(((size_t)b * splits + sp) * QN + q) * DVn + dv];
#pragma unroll 4
    for (int sp = 0; sp < splits * 4; ++sp)
        den += pden[((size_t)b * splits * 4 + sp) * QN + q];
    out[gid] = sum / (den + 1e-8f);
}

}  // namespace

extern "C" void kernel_launch(void* const* d_in, const int* in_sizes, int n_in,
                              void* d_out, int out_size, void* d_ws, size_t ws_size,
                              hipStream_t stream) {
    const float* query = (const float*)d_in[0];
    const float* key   = (const float*)d_in[1];
    const float* value = (const float*)d_in[2];
    float* out = (float*)d_out;

    // Largest split count whose partials fit in d_ws (deterministic).
    int splits = MAX_SPLITS;
    auto need = [](int s) {
        return (size_t)Bn * s * QN * DVn * sizeof(float)
             + (size_t)Bn * s * 4 * QN * sizeof(float);
    };
    while (splits > 1 && need(splits) > ws_size) splits >>= 1;

    float* pout = (float*)d_ws;
    float* pden = pout + (size_t)Bn * splits * QN * DVn;

    const int ntiles = KVn / (splits * TILE);   // 8 at splits=32 (always even)

    dim3 grid1(splits, Bn);
    inv_attn_part<<<grid1, THREADS, 0, stream>>>(query, key, value, pout, pden, ntiles);

    const int total = Bn * QN * DVn;   // 65536
    inv_attn_reduce<<<total / 256, 256, 0, stream>>>(pout, pden, out, splits);
}

// Round 7
// 118.749 us; speedup vs baseline: 1.0422x; 1.0209x over previous
//
#include <hip/hip_runtime.h>

namespace {

typedef float f32x4 __attribute__((ext_vector_type(4)));
typedef short bf16x8 __attribute__((ext_vector_type(8)));

constexpr int Bn = 64, QN = 16, Dn = 64, DVn = 64, KVn = 16384;
constexpr int SPLITS  = 16;
constexpr int TILE    = 64;                     // keys per block tile (16/wave)
constexpr int THREADS = 256;                    // 4 independent waves
constexpr int NT      = KVn / (SPLITS * TILE);  // 16 tiles per block
constexpr int NPAIRS  = NT / 2;                 // 8
constexpr int PTP     = 20;                     // pT row pitch (floats)
constexpr int SPLITS4 = SPLITS * 4;             // per-wave partials

constexpr float SCALE = 0.125f * 1.4426950408889634f;  // 1/sqrt(64) * log2(e)

#define MFMA16x32 __builtin_amdgcn_mfma_f32_16x16x32_bf16

__device__ __forceinline__ unsigned cvt_pk_bf16(float a, float b) {
    unsigned r;
    asm("v_cvt_pk_bf16_f32 %0, %1, %2" : "=v"(r) : "v"(a), "v"(b));
    return r;
}

union FragU { unsigned u[4]; bf16x8 v; };

// split 8 fp32 into hi/lo bf16x8 fragments (hi = rne-bf16, lo = bf16(x - hi))
__device__ __forceinline__ void split8(const float* x, bf16x8& hi, bf16x8& lo) {
    FragU uh, ul;
#pragma unroll
    for (int p = 0; p < 4; ++p) {
        const float a = x[2 * p], b = x[2 * p + 1];
        const unsigned h = cvt_pk_bf16(a, b);
        uh.u[p] = h;
        const float ha = __uint_as_float(h << 16);
        const float hb = __uint_as_float(h & 0xffff0000u);
        ul.u[p] = cvt_pk_bf16(a - ha, b - hb);
    }
    hi = uh.v; lo = ul.v;
}

// async 16B/lane global->LDS DMA (dest = lds base + lane*16, src per-lane)
__device__ __forceinline__ void gl_lds16(const float* g, const char* l) {
    __builtin_amdgcn_global_load_lds(
        (const __attribute__((address_space(1))) unsigned int*)g,
        (__attribute__((address_space(3))) unsigned int*)l,
        16, 0, 0);
}

// Barrier-free streaming kernel: each wave = independent split over its own
// 16 keys per tile. K/V stream via global_load_lds (3-slot ring, counted
// vmcnt waits, never a __syncthreads -> no vmcnt(0) drains).
__global__ __launch_bounds__(THREADS)
void inv_attn_part(const float* __restrict__ query,
                   const float* __restrict__ key,
                   const float* __restrict__ value,
                   float* __restrict__ pout,   // [B][SPLITS4][QN][DVn]
                   float* __restrict__ pden)   // [B][SPLITS4][QN]
{
    // 3 slots x 4 waves x {K,V} x 4KB (16 rows x 256B, 16B-chunk-swizzled)
    __shared__ __align__(16) char  kv[3][4][2][4096];   // 96 KB
    __shared__ __align__(16) float pT[4][32 * PTP];     // 10.25 KB (wave-private)

    const int tid  = threadIdx.x;
    const int lane = tid & 63;
    const int w    = tid >> 6;
    const int l15  = lane & 15;
    const int g    = lane >> 4;
    const int spl  = blockIdx.x;
    const int b    = blockIdx.y;
    const int kt0  = spl * (NT * TILE);

    // ---- Q fragments (loads consumed here, before any DMA is issued) ----
    bf16x8 qhi[2], qlo[2];
    {
        const float* qp = query + ((size_t)b * QN + l15) * Dn + g * 8;
#pragma unroll
        for (int ks = 0; ks < 2; ++ks) {
            const float4 u0 = *reinterpret_cast<const float4*>(qp + ks * 32);
            const float4 u1 = *reinterpret_cast<const float4*>(qp + ks * 32 + 4);
            float x[8] = {u0.x * SCALE, u0.y * SCALE, u0.z * SCALE, u0.w * SCALE,
                          u1.x * SCALE, u1.y * SCALE, u1.z * SCALE, u1.w * SCALE};
            split8(x, qhi[ks], qlo[ks]);
        }
    }
    __builtin_amdgcn_sched_barrier(0);   // Q loads fully retired before DMAs

    // ---- staging constants: DMA lane l covers row i*4+(l>>4), chunk l&15;
    //      source chunk pre-swizzled so LDS chunk p holds logical p^(row&7) ----
    const int srow = lane >> 4;
    const int sp   = lane & 15;
    const float* kg = key   + ((size_t)b * KVn + kt0 + w * 16) * Dn;
    const float* vg = value + ((size_t)b * KVn + kt0 + w * 16) * Dn;

    auto issue_tile = [&](int t, int slot) {
        const char* kb = &kv[slot][w][0][0];
        const char* vb = &kv[slot][w][1][0];
        const size_t toff = (size_t)t * TILE * Dn;
#pragma unroll
        for (int i = 0; i < 4; ++i) {
            const int perm = sp ^ srow ^ (4 * (i & 1));      // == sp ^ (row&7)
            const size_t off = toff + (size_t)(i * 4 + srow) * Dn + perm * 4;
            gl_lds16(kg + off, kb + i * 1024);
            gl_lds16(vg + off, vb + i * 1024);
        }
        __builtin_amdgcn_sched_barrier(0);   // keep DMA issue order = tile order
    };

    // ---- QK^T + softmax for one 16-key tile (wave-local; r4-validated) ----
    auto qk_softmax = [&](int slot) -> f32x4 {
        const char* kb = &kv[slot][w][0][0];
        const int sw = l15 & 7;
        f32x4 sacc = {0.f, 0.f, 0.f, 0.f};
#pragma unroll
        for (int ks = 0; ks < 2; ++ks) {
            const int c0 = ks * 8 + g * 2;
            const f32x4 r0 = *reinterpret_cast<const f32x4*>(
                kb + l15 * 256 + ((c0    ) ^ sw) * 16);
            const f32x4 r1 = *reinterpret_cast<const f32x4*>(
                kb + l15 * 256 + ((c0 + 1) ^ sw) * 16);
            float x[8] = {r0[0], r0[1], r0[2], r0[3], r1[0], r1[1], r1[2], r1[3]};
            bf16x8 khi, klo;
            split8(x, khi, klo);
            sacc = MFMA16x32(qhi[ks], khi, sacc, 0, 0, 0);
            sacc = MFMA16x32(qhi[ks], klo, sacc, 0, 0, 0);
            sacc = MFMA16x32(qlo[ks], khi, sacc, 0, 0, 0);
        }
        float m = fmaxf(fmaxf(sacc[0], sacc[1]), fmaxf(sacc[2], sacc[3]));
        m = fmaxf(m, __shfl_xor(m, 16, 64));
        m = fmaxf(m, __shfl_xor(m, 32, 64));
        f32x4 pr;
        pr[0] = exp2f(sacc[0] - m); pr[1] = exp2f(sacc[1] - m);
        pr[2] = exp2f(sacc[2] - m); pr[3] = exp2f(sacc[3] - m);
        float s = pr[0] + pr[1] + pr[2] + pr[3];
        s += __shfl_xor(s, 16, 64);
        s += __shfl_xor(s, 32, 64);
        const float inv = 1.0f / s;
        pr[0] *= inv; pr[1] *= inv; pr[2] *= inv; pr[3] *= inv;
        return pr;   // P[q=g*4+r][key=l15]
    };

    // ---- prologue: 3 tiles in flight ----
    issue_tile(0, 0);
    issue_tile(1, 1);
    issue_tile(2, 2);

    f32x4 o0 = {0.f,0.f,0.f,0.f}, o1 = {0.f,0.f,0.f,0.f},
          o2 = {0.f,0.f,0.f,0.f}, o3 = {0.f,0.f,0.f,0.f};
    f32x4 den = {0.f,0.f,0.f,0.f};
    float* pTw = &pT[w][0];

    int s0 = 0, s1 = 1, s2 = 2;   // pair uses s0,s1; s2 holds the tile in flight
    for (int p = 0; p < NPAIRS; ++p) {
        // counted wait: pair's 2 tiles resident; later tiles stay in flight
        if (p == NPAIRS - 1) { asm volatile("s_waitcnt vmcnt(0)" ::: "memory"); }
        else                 { asm volatile("s_waitcnt vmcnt(8)" ::: "memory"); }
        __builtin_amdgcn_sched_barrier(0);

        // QK + softmax, both tiles; transpose P via wave-private LDS
        const f32x4 pA = qk_softmax(s0);
        *reinterpret_cast<f32x4*>(&pTw[l15 * PTP + g * 4]) = pA;
        const f32x4 pB = qk_softmax(s1);
        *reinterpret_cast<f32x4*>(&pTw[(16 + l15) * PTP + g * 4]) = pB;
        den[0] += pA[0] + pB[0]; den[1] += pA[1] + pB[1];
        den[2] += pA[2] + pB[2]; den[3] += pA[3] + pB[3];

        // A-frag: P[q=l15][k=g*8+j] over the pair's 32 keys (r5-validated)
        float ax[8];
#pragma unroll
        for (int j = 0; j < 8; ++j) ax[j] = pTw[(g * 8 + j) * PTP + l15];
        FragU ua;
        ua.u[0] = cvt_pk_bf16(ax[0], ax[1]);
        ua.u[1] = cvt_pk_bf16(ax[2], ax[3]);
        ua.u[2] = cvt_pk_bf16(ax[4], ax[5]);
        ua.u[3] = cvt_pk_bf16(ax[6], ax[7]);

        // B-frag: V[k=g*8+j][dv=c*16+l15]; k<16 -> tile s0, k>=16 -> tile s1
        const char* vb = &kv[(g < 2) ? s0 : s1][w][1][0];
        const int rbase = (g & 1) * 8;
        const int cb = l15 >> 2;
        const int wb = (l15 & 3) * 4;
#pragma unroll
        for (int c = 0; c < 4; ++c) {
            float vx[8];
#pragma unroll
            for (int j = 0; j < 8; ++j) {
                const int addr = (rbase + j) * 256 + (((c * 4 + cb) ^ j) << 4) + wb;
                vx[j] = *reinterpret_cast<const float*>(vb + addr);
            }
            FragU uv;
            uv.u[0] = cvt_pk_bf16(vx[0], vx[1]);
            uv.u[1] = cvt_pk_bf16(vx[2], vx[3]);
            uv.u[2] = cvt_pk_bf16(vx[4], vx[5]);
            uv.u[3] = cvt_pk_bf16(vx[6], vx[7]);
            f32x4& oc = (c == 0) ? o0 : (c == 1) ? o1 : (c == 2) ? o2 : o3;
            oc = MFMA16x32(ua.v, uv.v, oc, 0, 0, 0);
        }

        // slots s0,s1 fully consumed -> refill with tiles 2p+3, 2p+4
        const int tn0 = 2 * p + 3, tn1 = 2 * p + 4;
        if (tn0 < NT) issue_tile(tn0, s0);
        if (tn1 < NT) issue_tile(tn1, s1);

        const int os0 = s0, os1 = s1;
        s0 = s2; s1 = os0; s2 = os1;   // next pair: tiles 2p+2 (old s2), 2p+3
    }

    // ---- per-wave partial O: O[q=g*4+r][dv=c*16+l15], split id = spl*4+w ----
    const size_t obase = (((size_t)b * SPLITS4 + spl * 4 + w) * QN) * DVn;
#pragma unroll
    for (int r = 0; r < 4; ++r) {
        const int q = g * 4 + r;
        pout[obase + q * DVn +  0 + l15] = o0[r];
        pout[obase + q * DVn + 16 + l15] = o1[r];
        pout[obase + q * DVn + 32 + l15] = o2[r];
        pout[obase + q * DVn + 48 + l15] = o3[r];
    }

    // ---- denominator: reduce over the 16 keys (l15 axis) ----
#pragma unroll
    for (int off = 1; off < 16; off <<= 1) {
        den[0] += __shfl_xor(den[0], off, 64);
        den[1] += __shfl_xor(den[1], off, 64);
        den[2] += __shfl_xor(den[2], off, 64);
        den[3] += __shfl_xor(den[3], off, 64);
    }
    if (l15 == 0) {
        const size_t dbase = ((size_t)b * SPLITS4 + spl * 4 + w) * QN + g * 4;
        pden[dbase + 0] = den[0];
        pden[dbase + 1] = den[1];
        pden[dbase + 2] = den[2];
        pden[dbase + 3] = den[3];
    }
}

__global__ __launch_bounds__(256)
void inv_attn_reduce(const float* __restrict__ pout,
                     const float* __restrict__ pden,
                     float* __restrict__ out)
{
    const int gid = blockIdx.x * blockDim.x + threadIdx.x;   // 0..65535
    const int dv = gid & 63;
    const int q  = (gid >> 6) & (QN - 1);
    const int b  = gid >> 10;
    float sum = 0.f, den = 0.f;
#pragma unroll 4
    for (int sp = 0; sp < SPLITS4; ++sp) {
        sum += pout[(((size_t)b * SPLITS4 + sp) * QN + q) * DVn + dv];
        den += pden[((size_t)b * SPLITS4 + sp) * QN + q];
    }
    out[gid] = sum / (den + 1e-8f);
}

}  // namespace

extern "C" void kernel_launch(void* const* d_in, const int* in_sizes, int n_in,
                              void* d_out, int out_size, void* d_ws, size_t ws_size,
                              hipStream_t stream) {
    const float* query = (const float*)d_in[0];
    const float* key   = (const float*)d_in[1];
    const float* value = (const float*)d_in[2];
    float* out = (float*)d_out;

    // partials: 16.8 MB + 0.26 MB (ws proven >= 34 MB in earlier rounds)
    float* pout = (float*)d_ws;
    float* pden = pout + (size_t)Bn * SPLITS4 * QN * DVn;

    dim3 grid1(SPLITS, Bn);
    inv_attn_part<<<grid1, THREADS, 0, stream>>>(query, key, value, pout, pden);

    const int total = Bn * QN * DVn;   // 65536
    inv_attn_reduce<<<total / 256, 256, 0, stream>>>(pout, pden, out);
}

// Round 8
// 107.982 us; speedup vs baseline: 1.1461x; 1.0997x over previous
//
#include <hip/hip_runtime.h>

namespace {

typedef float f32x4 __attribute__((ext_vector_type(4)));
typedef short bf16x8 __attribute__((ext_vector_type(8)));

constexpr int Bn = 64, QN = 16, Dn = 64, DVn = 64, KVn = 16384;
constexpr int MAX_SPLITS = 16;
constexpr int TILE    = 64;     // keys per tile
constexpr int THREADS = 256;    // 4 waves
constexpr int AP   = 68;        // probs LDS row pitch (floats): 272B = 17*16B
constexpr int VROW = 160;       // vT row pitch in BYTES: 128B data + 32B pad

constexpr float SCALE = 0.125f * 1.4426950408889634f;  // 1/sqrt(64) * log2(e)

__device__ __forceinline__ unsigned cvt_pk_bf16(float a, float b) {
    unsigned r;
    asm("v_cvt_pk_bf16_f32 %0, %1, %2" : "=v"(r) : "v"(a), "v"(b));
    return r;
}

union FragU { unsigned u[4]; bf16x8 v; };

// split 8 fp32 into hi/lo bf16x8 fragments (hi = rne-bf16, lo = bf16(x - hi))
__device__ __forceinline__ void split8(const float* x, bf16x8& hi, bf16x8& lo) {
    FragU uh, ul;
#pragma unroll
    for (int p = 0; p < 4; ++p) {
        const float a = x[2 * p], b2 = x[2 * p + 1];
        const unsigned h = cvt_pk_bf16(a, b2);
        uh.u[p] = h;
        const float ha = __uint_as_float(h << 16);
        const float hb = __uint_as_float(h & 0xffff0000u);
        ul.u[p] = cvt_pk_bf16(a - ha, b2 - hb);
    }
    hi = uh.v; lo = ul.v;
}

__global__ __launch_bounds__(THREADS, 4)
void inv_attn_part(const float* __restrict__ query,
                   const float* __restrict__ key,
                   const float* __restrict__ value,
                   float* __restrict__ pout,   // [B][splits][QN][DVn]
                   float* __restrict__ pden,   // [B][splits][QN]
                   int ntiles)
{
    // LDS: P buffer (fp32) + V^T (bf16, swizzled), double-buffered (r4-validated).
    __shared__ __align__(16) float a_s[2][QN * AP];        // 2 x 4.35 KB
    __shared__ __align__(16) char  vT[2][DVn * VROW];      // 2 x 10.0 KB
    __shared__ float den_buf[4][QN];

    const int tid  = threadIdx.x;
    const int lane = tid & 63;
    const int w    = tid >> 6;          // wave id: keys w*16.. (QK) / dv w*16.. (PV)
    const int l15  = lane & 15;
    const int g    = lane >> 4;         // k-chunk group for MFMA frags
    const int spl  = blockIdx.x;
    const int splits = gridDim.x;
    const int b    = blockIdx.y;
    const int kt0  = spl * ntiles * TILE;

    // ---- hoist Q fragments (A-frag: row=l15=q, k=ks*32+g*8+j; validated) ----
    bf16x8 qhi[2], qlo[2];
    {
        const float* qp = query + ((size_t)b * QN + l15) * Dn + g * 8;
#pragma unroll
        for (int ks = 0; ks < 2; ++ks) {
            const float4 u0 = *reinterpret_cast<const float4*>(qp + ks * 32);
            const float4 u1 = *reinterpret_cast<const float4*>(qp + ks * 32 + 4);
            float x[8] = { u0.x * SCALE, u0.y * SCALE, u0.z * SCALE, u0.w * SCALE,
                           u1.x * SCALE, u1.y * SCALE, u1.z * SCALE, u1.w * SCALE };
            split8(x, qhi[ks], qlo[ks]);
        }
    }

    f32x4 oacc = {0.f, 0.f, 0.f, 0.f};          // O[q=g*4+r][dv=w*16+l15]
    float den0 = 0.f, den1 = 0.f, den2 = 0.f, den3 = 0.f;

    // V staging map: thread stages row-pairs (2*vkey + {0,1}) and (+32), cols
    // vdv0..vdv0+3; packs k,k+1 into one ds_write_b32 (8 writes vs r4's 16 b16).
    const int vkey = tid >> 4;                  // 0..15
    const int vdv0 = (tid & 15) * 4;
    const int vsw  = ((tid & 15) & 7) << 4;     // XOR swizzle = ((dv>>2)&7)<<4

    // K fragment source: this lane's key row (+ g*8 element offset)
    const float* kbase = key   + ((size_t)b * KVn + kt0 + w * 16 + l15) * Dn + g * 8;
    const float* vbase = value + ((size_t)b * KVn + kt0 + 2 * vkey) * Dn + vdv0;

    for (int t = 0; t < ntiles; ++t) {
        const int buf = t & 1;

        // ---- stage V tile: fp32 -> bf16 pairs, transposed into vT[dv][k] ----
        float4 vv[2][2];   // [i = row-block 0/1 (+32)] [rr = row parity]
#pragma unroll
        for (int i = 0; i < 2; ++i)
#pragma unroll
            for (int rr = 0; rr < 2; ++rr)
                vv[i][rr] = *reinterpret_cast<const float4*>(
                    vbase + ((size_t)t * TILE + 32 * i + rr) * Dn);
#pragma unroll
        for (int i = 0; i < 2; ++i) {
            const int kbyte = 4 * vkey + 64 * i;    // byte offset of k0=2*vkey+32i
#pragma unroll
            for (int j = 0; j < 4; ++j) {
                const float x0 = (j == 0) ? vv[i][0].x : (j == 1) ? vv[i][0].y
                                : (j == 2) ? vv[i][0].z : vv[i][0].w;
                const float x1 = (j == 0) ? vv[i][1].x : (j == 1) ? vv[i][1].y
                                : (j == 2) ? vv[i][1].z : vv[i][1].w;
                *reinterpret_cast<unsigned*>(
                    &vT[buf][(vdv0 + j) * VROW + (kbyte ^ vsw)]) =
                    cvt_pk_bf16(x0, x1);
            }
        }

        // ---- QK^T via MFMA: S[q][key], A=Q (regs), B=K (global, hi/lo split) ----
        f32x4 sacc = {0.f, 0.f, 0.f, 0.f};
#pragma unroll
        for (int ks = 0; ks < 2; ++ks) {
            const float4 ka = *reinterpret_cast<const float4*>(kbase + (size_t)t * TILE * Dn + ks * 32);
            const float4 kb = *reinterpret_cast<const float4*>(kbase + (size_t)t * TILE * Dn + ks * 32 + 4);
            float x[8] = { ka.x, ka.y, ka.z, ka.w, kb.x, kb.y, kb.z, kb.w };
            bf16x8 khi, klo;
            split8(x, khi, klo);
            sacc = __builtin_amdgcn_mfma_f32_16x16x32_bf16(qhi[ks], khi, sacc, 0, 0, 0);
            sacc = __builtin_amdgcn_mfma_f32_16x16x32_bf16(qhi[ks], klo, sacc, 0, 0, 0);
            sacc = __builtin_amdgcn_mfma_f32_16x16x32_bf16(qlo[ks], khi, sacc, 0, 0, 0);
        }

        // ---- softmax over q (16) for key = kt0 + t*64 + w*16 + l15 ----
        float m = fmaxf(fmaxf(sacc[0], sacc[1]), fmaxf(sacc[2], sacc[3]));
        m = fmaxf(m, __shfl_xor(m, 16, 64));
        m = fmaxf(m, __shfl_xor(m, 32, 64));
        float p0 = exp2f(sacc[0] - m), p1 = exp2f(sacc[1] - m);
        float p2 = exp2f(sacc[2] - m), p3 = exp2f(sacc[3] - m);
        float s4 = p0 + p1 + p2 + p3;
        s4 += __shfl_xor(s4, 16, 64);
        s4 += __shfl_xor(s4, 32, 64);
        const float inv = 1.0f / s4;
        p0 *= inv; p1 *= inv; p2 *= inv; p3 *= inv;
        const int kloc = w * 16 + l15;
        a_s[buf][(g * 4 + 0) * AP + kloc] = p0;
        a_s[buf][(g * 4 + 1) * AP + kloc] = p1;
        a_s[buf][(g * 4 + 2) * AP + kloc] = p2;
        a_s[buf][(g * 4 + 3) * AP + kloc] = p3;
        den0 += p0; den1 += p1; den2 += p2; den3 += p3;

        __syncthreads();   // probs + vT of tile t visible; prev-buf reads done

        // ---- PV via MFMA: O[q][dv] += P[q][key] * V[key][dv] ----
#pragma unroll
        for (int ks = 0; ks < 2; ++ks) {
            const int base = ks * 32 + g * 8;
            const float4 a0 = *reinterpret_cast<const float4*>(&a_s[buf][l15 * AP + base]);
            const float4 a1 = *reinterpret_cast<const float4*>(&a_s[buf][l15 * AP + base + 4]);
            FragU ua;
            ua.u[0] = cvt_pk_bf16(a0.x, a0.y);
            ua.u[1] = cvt_pk_bf16(a0.z, a0.w);
            ua.u[2] = cvt_pk_bf16(a1.x, a1.y);
            ua.u[3] = cvt_pk_bf16(a1.z, a1.w);
            const int dv = w * 16 + l15;
            const int gran = (((ks * 4 + g) ^ ((dv >> 2) & 7)) << 4);
            const bf16x8 vf = *reinterpret_cast<const bf16x8*>(&vT[buf][dv * VROW + gran]);
            oacc = __builtin_amdgcn_mfma_f32_16x16x32_bf16(ua.v, vf, oacc, 0, 0, 0);
        }
    }

    // ---- write partial outputs: O[q=g*4+r][dv=w*16+l15] ----
    const size_t obase = (((size_t)b * splits + spl) * QN) * DVn;
    const int dv = w * 16 + l15;
    pout[obase + (g * 4 + 0) * DVn + dv] = oacc[0];
    pout[obase + (g * 4 + 1) * DVn + dv] = oacc[1];
    pout[obase + (g * 4 + 2) * DVn + dv] = oacc[2];
    pout[obase + (g * 4 + 3) * DVn + dv] = oacc[3];

    // ---- denominator: reduce over the 16 keys (l15) within the wave ----
#pragma unroll
    for (int off = 1; off < 16; off <<= 1) {
        den0 += __shfl_xor(den0, off, 64);
        den1 += __shfl_xor(den1, off, 64);
        den2 += __shfl_xor(den2, off, 64);
        den3 += __shfl_xor(den3, off, 64);
    }
    if (l15 == 0) {
        den_buf[w][g * 4 + 0] = den0;
        den_buf[w][g * 4 + 1] = den1;
        den_buf[w][g * 4 + 2] = den2;
        den_buf[w][g * 4 + 3] = den3;
    }
    __syncthreads();
    if (tid < QN) {
        const float d = den_buf[0][tid] + den_buf[1][tid] + den_buf[2][tid] + den_buf[3][tid];
        pden[((size_t)b * splits + spl) * QN + tid] = d;
    }
}

__global__ __launch_bounds__(256)
void inv_attn_reduce(const float* __restrict__ pout,
                     const float* __restrict__ pden,
                     float* __restrict__ out,
                     int splits)
{
    const int gid = blockIdx.x * blockDim.x + threadIdx.x;   // 0..65535
    const int dv = gid & 63;
    const int q  = (gid >> 6) & (QN - 1);
    const int b  = gid >> 10;
    float sum = 0.f, den = 0.f;
#pragma unroll 8
    for (int sp = 0; sp < splits; ++sp) {
        sum += pout[(((size_t)b * splits + sp) * QN + q) * DVn + dv];
        den += pden[((size_t)b * splits + sp) * QN + q];
    }
    out[gid] = sum / (den + 1e-8f);
}

}  // namespace

extern "C" void kernel_launch(void* const* d_in, const int* in_sizes, int n_in,
                              void* d_out, int out_size, void* d_ws, size_t ws_size,
                              hipStream_t stream) {
    const float* query = (const float*)d_in[0];
    const float* key   = (const float*)d_in[1];
    const float* value = (const float*)d_in[2];
    float* out = (float*)d_out;

    int splits = MAX_SPLITS;
    auto need = [](int s) {
        return (size_t)Bn * s * QN * DVn * sizeof(float)
             + (size_t)Bn * s * QN * sizeof(float);
    };
    while (splits > 1 && need(splits) > ws_size) splits >>= 1;

    float* pout = (float*)d_ws;
    float* pden = pout + (size_t)Bn * splits * QN * DVn;

    const int ntiles = KVn / (splits * TILE);   // 16 at splits=16

    dim3 grid1(splits, Bn);
    inv_attn_part<<<grid1, THREADS, 0, stream>>>(query, key, value, pout, pden, ntiles);

    const int total = Bn * QN * DVn;   // 65536
    inv_attn_reduce<<<total / 256, 256, 0, stream>>>(pout, pden, out, splits);
}

// Round 10
// 105.471 us; speedup vs baseline: 1.1734x; 1.0238x over previous
//
#include <hip/hip_runtime.h>

namespace {

typedef float f32x4 __attribute__((ext_vector_type(4)));
typedef short bf16x8 __attribute__((ext_vector_type(8)));

constexpr int Bn = 64, QN = 16, Dn = 64, DVn = 64, KVn = 16384;
constexpr int MAX_SPLITS = 16;
constexpr int TILE    = 64;     // keys per tile
constexpr int THREADS = 256;    // 4 waves
constexpr int AP   = 68;        // probs LDS row pitch (floats): 272B = 17*16B
constexpr int VROW = 160;       // vT row pitch in BYTES: 128B data + 32B pad

constexpr float SCALE = 0.125f * 1.4426950408889634f;  // 1/sqrt(64) * log2(e)

__device__ __forceinline__ unsigned cvt_pk_bf16(float a, float b) {
    unsigned r;
    asm("v_cvt_pk_bf16_f32 %0, %1, %2" : "=v"(r) : "v"(a), "v"(b));
    return r;
}

union FragU { unsigned u[4]; bf16x8 v; };

// split 8 fp32 into hi/lo bf16x8 fragments (hi = rne-bf16, lo = bf16(x - hi))
__device__ __forceinline__ void split8(const float* x, bf16x8& hi, bf16x8& lo) {
    FragU uh, ul;
#pragma unroll
    for (int p = 0; p < 4; ++p) {
        const float a = x[2 * p], b2 = x[2 * p + 1];
        const unsigned h = cvt_pk_bf16(a, b2);
        uh.u[p] = h;
        const float ha = __uint_as_float(h << 16);
        const float hb = __uint_as_float(h & 0xffff0000u);
        ul.u[p] = cvt_pk_bf16(a - ha, b2 - hb);
    }
    hi = uh.v; lo = ul.v;
}

__global__ __launch_bounds__(THREADS, 4)
void inv_attn_part(const float* __restrict__ query,
                   const float* __restrict__ key,
                   const float* __restrict__ value,
                   float* __restrict__ pout,   // [B][splits][QN][DVn]
                   float* __restrict__ pden,   // [B][splits][QN]
                   int ntiles)
{
    // LDS: P buffer (fp32) + V^T (bf16, swizzled), double-buffered (r4-validated).
    __shared__ __align__(16) float a_s[2][QN * AP];        // 2 x 4.35 KB
    __shared__ __align__(16) char  vT[2][DVn * VROW];      // 2 x 10.0 KB
    __shared__ float den_buf[4][QN];

    const int tid  = threadIdx.x;
    const int lane = tid & 63;
    const int w    = tid >> 6;          // wave id: keys w*16.. (QK) / dv w*16.. (PV)
    const int l15  = lane & 15;
    const int g    = lane >> 4;         // k-chunk group for MFMA frags
    const int spl  = blockIdx.x;
    const int splits = gridDim.x;
    const int b    = blockIdx.y;
    const int kt0  = spl * ntiles * TILE;

    // ---- hoist Q fragments (A-frag: row=l15=q, k=ks*32+g*8+j; validated) ----
    bf16x8 qhi[2], qlo[2];
    {
        const float* qp = query + ((size_t)b * QN + l15) * Dn + g * 8;
#pragma unroll
        for (int ks = 0; ks < 2; ++ks) {
            const float4 u0 = *reinterpret_cast<const float4*>(qp + ks * 32);
            const float4 u1 = *reinterpret_cast<const float4*>(qp + ks * 32 + 4);
            float x[8] = { u0.x * SCALE, u0.y * SCALE, u0.z * SCALE, u0.w * SCALE,
                           u1.x * SCALE, u1.y * SCALE, u1.z * SCALE, u1.w * SCALE };
            split8(x, qhi[ks], qlo[ks]);
        }
    }

    f32x4 oacc = {0.f, 0.f, 0.f, 0.f};          // O[q=g*4+r][dv=w*16+l15]
    float den0 = 0.f, den1 = 0.f, den2 = 0.f, den3 = 0.f;

    // V staging map: thread stages row-pairs (2*vkey + {0,1}) and (+32), cols
    // vdv0..vdv0+3; packs k,k+1 into one ds_write_b32 (8 writes vs r4's 16 b16).
    const int vkey = tid >> 4;                  // 0..15
    const int vdv0 = (tid & 15) * 4;
    const int vsw  = ((tid & 15) & 7) << 4;     // XOR swizzle = ((dv>>2)&7)<<4

    // K fragment source: this lane's key row (+ g*8 element offset)
    const float* kbase = key   + ((size_t)b * KVn + kt0 + w * 16 + l15) * Dn + g * 8;
    const float* vbase = value + ((size_t)b * KVn + kt0 + 2 * vkey) * Dn + vdv0;

    for (int t = 0; t < ntiles; ++t) {
        const int buf = t & 1;

        // ---- stage V tile: fp32 -> bf16 pairs, transposed into vT[dv][k] ----
        float4 vv[2][2];   // [i = row-block 0/1 (+32)] [rr = row parity]
#pragma unroll
        for (int i = 0; i < 2; ++i)
#pragma unroll
            for (int rr = 0; rr < 2; ++rr)
                vv[i][rr] = *reinterpret_cast<const float4*>(
                    vbase + ((size_t)t * TILE + 32 * i + rr) * Dn);
#pragma unroll
        for (int i = 0; i < 2; ++i) {
            const int kbyte = 4 * vkey + 64 * i;    // byte offset of k0=2*vkey+32i
#pragma unroll
            for (int j = 0; j < 4; ++j) {
                const float x0 = (j == 0) ? vv[i][0].x : (j == 1) ? vv[i][0].y
                                : (j == 2) ? vv[i][0].z : vv[i][0].w;
                const float x1 = (j == 0) ? vv[i][1].x : (j == 1) ? vv[i][1].y
                                : (j == 2) ? vv[i][1].z : vv[i][1].w;
                *reinterpret_cast<unsigned*>(
                    &vT[buf][(vdv0 + j) * VROW + (kbyte ^ vsw)]) =
                    cvt_pk_bf16(x0, x1);
            }
        }

        // ---- QK^T via MFMA: S[q][key], A=Q (regs), B=K (global, hi/lo split) ----
        f32x4 sacc = {0.f, 0.f, 0.f, 0.f};
#pragma unroll
        for (int ks = 0; ks < 2; ++ks) {
            const float4 ka = *reinterpret_cast<const float4*>(kbase + (size_t)t * TILE * Dn + ks * 32);
            const float4 kb = *reinterpret_cast<const float4*>(kbase + (size_t)t * TILE * Dn + ks * 32 + 4);
            float x[8] = { ka.x, ka.y, ka.z, ka.w, kb.x, kb.y, kb.z, kb.w };
            bf16x8 khi, klo;
            split8(x, khi, klo);
            sacc = __builtin_amdgcn_mfma_f32_16x16x32_bf16(qhi[ks], khi, sacc, 0, 0, 0);
            sacc = __builtin_amdgcn_mfma_f32_16x16x32_bf16(qhi[ks], klo, sacc, 0, 0, 0);
            sacc = __builtin_amdgcn_mfma_f32_16x16x32_bf16(qlo[ks], khi, sacc, 0, 0, 0);
        }

        // ---- softmax over q (16) for key = kt0 + t*64 + w*16 + l15 ----
        float m = fmaxf(fmaxf(sacc[0], sacc[1]), fmaxf(sacc[2], sacc[3]));
        m = fmaxf(m, __shfl_xor(m, 16, 64));
        m = fmaxf(m, __shfl_xor(m, 32, 64));
        float p0 = exp2f(sacc[0] - m), p1 = exp2f(sacc[1] - m);
        float p2 = exp2f(sacc[2] - m), p3 = exp2f(sacc[3] - m);
        float s4 = p0 + p1 + p2 + p3;
        s4 += __shfl_xor(s4, 16, 64);
        s4 += __shfl_xor(s4, 32, 64);
        const float inv = 1.0f / s4;
        p0 *= inv; p1 *= inv; p2 *= inv; p3 *= inv;
        const int kloc = w * 16 + l15;
        a_s[buf][(g * 4 + 0) * AP + kloc] = p0;
        a_s[buf][(g * 4 + 1) * AP + kloc] = p1;
        a_s[buf][(g * 4 + 2) * AP + kloc] = p2;
        a_s[buf][(g * 4 + 3) * AP + kloc] = p3;
        den0 += p0; den1 += p1; den2 += p2; den3 += p3;

        __syncthreads();   // probs + vT of tile t visible; prev-buf reads done

        // ---- PV via MFMA: O[q][dv] += P[q][key] * V[key][dv] ----
#pragma unroll
        for (int ks = 0; ks < 2; ++ks) {
            const int base = ks * 32 + g * 8;
            const float4 a0 = *reinterpret_cast<const float4*>(&a_s[buf][l15 * AP + base]);
            const float4 a1 = *reinterpret_cast<const float4*>(&a_s[buf][l15 * AP + base + 4]);
            FragU ua;
            ua.u[0] = cvt_pk_bf16(a0.x, a0.y);
            ua.u[1] = cvt_pk_bf16(a0.z, a0.w);
            ua.u[2] = cvt_pk_bf16(a1.x, a1.y);
            ua.u[3] = cvt_pk_bf16(a1.z, a1.w);
            const int dv = w * 16 + l15;
            const int gran = (((ks * 4 + g) ^ ((dv >> 2) & 7)) << 4);
            const bf16x8 vf = *reinterpret_cast<const bf16x8*>(&vT[buf][dv * VROW + gran]);
            oacc = __builtin_amdgcn_mfma_f32_16x16x32_bf16(ua.v, vf, oacc, 0, 0, 0);
        }
    }

    // ---- write partial outputs: O[q=g*4+r][dv=w*16+l15] ----
    const size_t obase = (((size_t)b * splits + spl) * QN) * DVn;
    const int dv = w * 16 + l15;
    pout[obase + (g * 4 + 0) * DVn + dv] = oacc[0];
    pout[obase + (g * 4 + 1) * DVn + dv] = oacc[1];
    pout[obase + (g * 4 + 2) * DVn + dv] = oacc[2];
    pout[obase + (g * 4 + 3) * DVn + dv] = oacc[3];

    // ---- denominator: reduce over the 16 keys (l15) within the wave ----
#pragma unroll
    for (int off = 1; off < 16; off <<= 1) {
        den0 += __shfl_xor(den0, off, 64);
        den1 += __shfl_xor(den1, off, 64);
        den2 += __shfl_xor(den2, off, 64);
        den3 += __shfl_xor(den3, off, 64);
    }
    if (l15 == 0) {
        den_buf[w][g * 4 + 0] = den0;
        den_buf[w][g * 4 + 1] = den1;
        den_buf[w][g * 4 + 2] = den2;
        den_buf[w][g * 4 + 3] = den3;
    }
    __syncthreads();
    if (tid < QN) {
        const float d = den_buf[0][tid] + den_buf[1][tid] + den_buf[2][tid] + den_buf[3][tid];
        pden[((size_t)b * splits + spl) * QN + tid] = d;
    }
}

__global__ __launch_bounds__(256)
void inv_attn_reduce(const float* __restrict__ pout,
                     const float* __restrict__ pden,
                     float* __restrict__ out,
                     int splits)
{
    const int gid = blockIdx.x * blockDim.x + threadIdx.x;   // 0..65535
    const int dv = gid & 63;
    const int q  = (gid >> 6) & (QN - 1);
    const int b  = gid >> 10;
    float sum = 0.f, den = 0.f;
#pragma unroll 8
    for (int sp = 0; sp < splits; ++sp) {
        sum += pout[(((size_t)b * splits + sp) * QN + q) * DVn + dv];
        den += pden[((size_t)b * splits + sp) * QN + q];
    }
    out[gid] = sum / (den + 1e-8f);
}

}  // namespace

extern "C" void kernel_launch(void* const* d_in, const int* in_sizes, int n_in,
                              void* d_out, int out_size, void* d_ws, size_t ws_size,
                              hipStream_t stream) {
    const float* query = (const float*)d_in[0];
    const float* key   = (const float*)d_in[1];
    const float* value = (const float*)d_in[2];
    float* out = (float*)d_out;

    int splits = MAX_SPLITS;
    auto need = [](int s) {
        return (size_t)Bn * s * QN * DVn * sizeof(float)
             + (size_t)Bn * s * QN * sizeof(float);
    };
    while (splits > 1 && need(splits) > ws_size) splits >>= 1;

    float* pout = (float*)d_ws;
    float* pden = pout + (size_t)Bn * splits * QN * DVn;

    const int ntiles = KVn / (splits * TILE);   // 16 at splits=16

    dim3 grid1(splits, Bn);
    inv_attn_part<<<grid1, THREADS, 0, stream>>>(query, key, value, pout, pden, ntiles);

    const int total = Bn * QN * DVn;   // 65536
    inv_attn_reduce<<<total / 256, 256, 0, stream>>>(pout, pden, out, splits);
}

// Round 11
// 101.680 us; speedup vs baseline: 1.2172x; 1.0373x over previous
//
#include <hip/hip_runtime.h>

namespace {

typedef float f32x4 __attribute__((ext_vector_type(4)));
typedef short bf16x8 __attribute__((ext_vector_type(8)));

constexpr int Bn = 64, QN = 16, Dn = 64, DVn = 64, KVn = 16384;
constexpr int SPLITS  = 8;
constexpr int TILE    = 64;                     // keys per tile
constexpr int THREADS = 256;                    // 4 waves
constexpr int NT      = KVn / (SPLITS * TILE);  // 32 tiles per block
constexpr int AP      = 68;                     // a_s row pitch: 272B = 17*16B

constexpr float SCALE = 0.125f * 1.4426950408889634f;  // 1/sqrt(64) * log2(e)

__device__ __forceinline__ unsigned cvt_pk_bf16(float a, float b) {
    unsigned r;
    asm("v_cvt_pk_bf16_f32 %0, %1, %2" : "=v"(r) : "v"(a), "v"(b));
    return r;
}

union FragU { unsigned u[4]; bf16x8 v; };

// split 8 fp32 into hi/lo bf16x8 fragments (hi = rne-bf16, lo = bf16(x - hi))
__device__ __forceinline__ void split8(const float* x, bf16x8& hi, bf16x8& lo) {
    FragU uh, ul;
#pragma unroll
    for (int p = 0; p < 4; ++p) {
        const float a = x[2 * p], b2 = x[2 * p + 1];
        const unsigned h = cvt_pk_bf16(a, b2);
        uh.u[p] = h;
        const float ha = __uint_as_float(h << 16);
        const float hb = __uint_as_float(h & 0xffff0000u);
        ul.u[p] = cvt_pk_bf16(a - ha, b2 - hb);
    }
    hi = uh.v; lo = ul.v;
}

// async 16B/lane global->LDS DMA: dest = wave-uniform base + lane*16,
// src = per-lane global address (r7-validated helper).
__device__ __forceinline__ void gl_lds16(const float* g, float* l) {
    __builtin_amdgcn_global_load_lds(
        (const __attribute__((address_space(1))) unsigned int*)g,
        (__attribute__((address_space(3))) unsigned int*)l,
        16, 0, 0);
}

__global__ __launch_bounds__(THREADS, 2)
void inv_attn_part(const float* __restrict__ query,
                   const float* __restrict__ key,
                   const float* __restrict__ value,
                   float* __restrict__ pout,   // [B][SPLITS][QN][DVn]
                   float* __restrict__ pden)   // [B][SPLITS][QN]
{
    // K/V tiles staged RAW fp32 by global_load_lds, double-buffered.
    // Chunk swizzle (16B units): LDS chunk c of row r holds logical chunk
    // c ^ (r&7); applied on the GLOBAL SOURCE (rule: linear dest + pre-swz
    // src + swz read).
    __shared__ __align__(16) float kbuf[2][TILE * Dn];    // 2 x 16 KB
    __shared__ __align__(16) float vbuf[2][TILE * DVn];   // 2 x 16 KB
    __shared__ __align__(16) float a_s[2][QN * AP];       // 2 x 4.35 KB
    __shared__ float den_buf[4][QN];

    const int tid  = threadIdx.x;
    const int lane = tid & 63;
    const int w    = tid >> 6;          // wave: keys w*16.. (QK) / dv w*16.. (PV)
    const int l15  = lane & 15;
    const int g    = lane >> 4;
    const int spl  = blockIdx.x;
    const int b    = blockIdx.y;
    const int kt0  = spl * NT * TILE;

    // ---- hoist Q fragments (A-frag row=l15=q, k=ks*32+g*8+j; validated) ----
    bf16x8 qhi[2], qlo[2];
    {
        const float* qp = query + ((size_t)b * QN + l15) * Dn + g * 8;
#pragma unroll
        for (int ks = 0; ks < 2; ++ks) {
            const float4 u0 = *reinterpret_cast<const float4*>(qp + ks * 32);
            const float4 u1 = *reinterpret_cast<const float4*>(qp + ks * 32 + 4);
            float x[8] = {u0.x * SCALE, u0.y * SCALE, u0.z * SCALE, u0.w * SCALE,
                          u1.x * SCALE, u1.y * SCALE, u1.z * SCALE, u1.w * SCALE};
            split8(x, qhi[ks], qlo[ks]);
        }
    }

    f32x4 oacc = {0.f, 0.f, 0.f, 0.f};   // O[q=g*4+r][dv=w*16+l15]
    float den0 = 0.f, den1 = 0.f, den2 = 0.f, den3 = 0.f;

    // staging map: wave w stages rows w*16..+15; instr i covers rows
    // w*16+i*4 + (lane>>4), dest chunk lane&15, src chunk pre-swizzled.
    const int srow   = lane >> 4;
    const int schunk = lane & 15;
    const float* kg = key   + ((size_t)b * KVn + kt0) * Dn;
    const float* vg = value + ((size_t)b * KVn + kt0) * Dn;

    auto issue_tile = [&](int t, int buf) {
#pragma unroll
        for (int i = 0; i < 4; ++i) {
            const int r  = w * 16 + i * 4 + srow;        // row in tile
            const int sc = schunk ^ (r & 7);             // pre-swizzled src chunk
            const size_t off = (size_t)(t * TILE + r) * Dn + sc * 4;
            gl_lds16(kg + off, &kbuf[buf][(w * 16 + i * 4) * Dn]);
            gl_lds16(vg + off, &vbuf[buf][(w * 16 + i * 4) * DVn]);
        }
    };

    // ---- prologue: tile 0 in flight (drained by first barrier) ----
    issue_tile(0, 0);

    for (int t = 0; t < NT; ++t) {
        const int buf = t & 1;

        __syncthreads();   // B1: tile t staged+visible; all PV(t-1) reads done

        // issue tile t+1 into the other buffer; drains at B2 (QK+softmax
        // window hides most of the load latency; non-sinkable by compiler)
        if (t + 1 < NT) issue_tile(t + 1, buf ^ 1);

        // ---- QK^T from kbuf (swizzled b128 reads; hi/lo split, 6 MFMA) ----
        const int rq = w * 16 + l15;       // this lane's key row
        const int sw = rq & 7;
        f32x4 sacc = {0.f, 0.f, 0.f, 0.f};
#pragma unroll
        for (int ks = 0; ks < 2; ++ks) {
            const int c0 = ks * 8 + g * 2;
            const f32x4 r0 = *reinterpret_cast<const f32x4*>(
                &kbuf[buf][rq * Dn + ((c0    ) ^ sw) * 4]);
            const f32x4 r1 = *reinterpret_cast<const f32x4*>(
                &kbuf[buf][rq * Dn + ((c0 + 1) ^ sw) * 4]);
            float x[8] = {r0[0], r0[1], r0[2], r0[3], r1[0], r1[1], r1[2], r1[3]};
            bf16x8 khi, klo;
            split8(x, khi, klo);
            sacc = __builtin_amdgcn_mfma_f32_16x16x32_bf16(qhi[ks], khi, sacc, 0, 0, 0);
            sacc = __builtin_amdgcn_mfma_f32_16x16x32_bf16(qhi[ks], klo, sacc, 0, 0, 0);
            sacc = __builtin_amdgcn_mfma_f32_16x16x32_bf16(qlo[ks], khi, sacc, 0, 0, 0);
        }

        // ---- softmax over q (16) at key = kt0 + t*64 + rq (validated) ----
        float m = fmaxf(fmaxf(sacc[0], sacc[1]), fmaxf(sacc[2], sacc[3]));
        m = fmaxf(m, __shfl_xor(m, 16, 64));
        m = fmaxf(m, __shfl_xor(m, 32, 64));
        float p0 = exp2f(sacc[0] - m), p1 = exp2f(sacc[1] - m);
        float p2 = exp2f(sacc[2] - m), p3 = exp2f(sacc[3] - m);
        float s4 = p0 + p1 + p2 + p3;
        s4 += __shfl_xor(s4, 16, 64);
        s4 += __shfl_xor(s4, 32, 64);
        const float inv = 1.0f / s4;
        p0 *= inv; p1 *= inv; p2 *= inv; p3 *= inv;
        a_s[buf][(g * 4 + 0) * AP + rq] = p0;
        a_s[buf][(g * 4 + 1) * AP + rq] = p1;
        a_s[buf][(g * 4 + 2) * AP + rq] = p2;
        a_s[buf][(g * 4 + 3) * AP + rq] = p3;
        den0 += p0; den1 += p1; den2 += p2; den3 += p3;

        __syncthreads();   // B2: publish a_s; drains tile t+1's staging

        // ---- PV: O[q][dv] += P[q][key] * V[key][dv]; V from fp32 LDS ----
        const int dv = w * 16 + l15;
        const int ch = dv >> 2, wrd = dv & 3;
#pragma unroll
        for (int ks = 0; ks < 2; ++ks) {
            const int base = ks * 32 + g * 8;
            const float4 a0 = *reinterpret_cast<const float4*>(&a_s[buf][l15 * AP + base]);
            const float4 a1 = *reinterpret_cast<const float4*>(&a_s[buf][l15 * AP + base + 4]);
            FragU ua;
            ua.u[0] = cvt_pk_bf16(a0.x, a0.y);
            ua.u[1] = cvt_pk_bf16(a0.z, a0.w);
            ua.u[2] = cvt_pk_bf16(a1.x, a1.y);
            ua.u[3] = cvt_pk_bf16(a1.z, a1.w);
            float vx[8];
#pragma unroll
            for (int j = 0; j < 8; ++j) {
                const int k = base + j;                 // k&7 == j
                vx[j] = vbuf[buf][k * DVn + ((ch ^ j) << 2) + wrd];
            }
            FragU uv;
            uv.u[0] = cvt_pk_bf16(vx[0], vx[1]);
            uv.u[1] = cvt_pk_bf16(vx[2], vx[3]);
            uv.u[2] = cvt_pk_bf16(vx[4], vx[5]);
            uv.u[3] = cvt_pk_bf16(vx[6], vx[7]);
            oacc = __builtin_amdgcn_mfma_f32_16x16x32_bf16(ua.v, uv.v, oacc, 0, 0, 0);
        }
    }

    // ---- write partial outputs: O[q=g*4+r][dv=w*16+l15] ----
    const size_t obase = (((size_t)b * SPLITS + spl) * QN) * DVn;
    const int dvo = w * 16 + l15;
    pout[obase + (g * 4 + 0) * DVn + dvo] = oacc[0];
    pout[obase + (g * 4 + 1) * DVn + dvo] = oacc[1];
    pout[obase + (g * 4 + 2) * DVn + dvo] = oacc[2];
    pout[obase + (g * 4 + 3) * DVn + dvo] = oacc[3];

    // ---- denominator: reduce over the 16 keys (l15) within the wave ----
#pragma unroll
    for (int off = 1; off < 16; off <<= 1) {
        den0 += __shfl_xor(den0, off, 64);
        den1 += __shfl_xor(den1, off, 64);
        den2 += __shfl_xor(den2, off, 64);
        den3 += __shfl_xor(den3, off, 64);
    }
    if (l15 == 0) {
        den_buf[w][g * 4 + 0] = den0;
        den_buf[w][g * 4 + 1] = den1;
        den_buf[w][g * 4 + 2] = den2;
        den_buf[w][g * 4 + 3] = den3;
    }
    __syncthreads();
    if (tid < QN) {
        const float d = den_buf[0][tid] + den_buf[1][tid] + den_buf[2][tid] + den_buf[3][tid];
        pden[((size_t)b * SPLITS + spl) * QN + tid] = d;
    }
}

__global__ __launch_bounds__(256)
void inv_attn_reduce(const float* __restrict__ pout,
                     const float* __restrict__ pden,
                     float* __restrict__ out)
{
    const int gid = blockIdx.x * blockDim.x + threadIdx.x;   // 0..65535
    const int dv = gid & 63;
    const int q  = (gid >> 6) & (QN - 1);
    const int b  = gid >> 10;
    float sum = 0.f, den = 0.f;
#pragma unroll 8
    for (int sp = 0; sp < SPLITS; ++sp) {
        sum += pout[(((size_t)b * SPLITS + sp) * QN + q) * DVn + dv];
        den += pden[((size_t)b * SPLITS + sp) * QN + q];
    }
    out[gid] = sum / (den + 1e-8f);
}

}  // namespace

extern "C" void kernel_launch(void* const* d_in, const int* in_sizes, int n_in,
                              void* d_out, int out_size, void* d_ws, size_t ws_size,
                              hipStream_t stream) {
    const float* query = (const float*)d_in[0];
    const float* key   = (const float*)d_in[1];
    const float* value = (const float*)d_in[2];
    float* out = (float*)d_out;

    // partials: 2.0 MB + 32 KB (ws proven >= 1 GB by the harness poison fill)
    float* pout = (float*)d_ws;
    float* pden = pout + (size_t)Bn * SPLITS * QN * DVn;

    dim3 grid1(SPLITS, Bn);   // 512 blocks = 2/CU x 256 CU, single round
    inv_attn_part<<<grid1, THREADS, 0, stream>>>(query, key, value, pout, pden);

    const int total = Bn * QN * DVn;   // 65536
    inv_attn_reduce<<<total / 256, 256, 0, stream>>>(pout, pden, out);
}